// Round 1
// baseline (686.277 us; speedup 1.0000x reference)
//
#include <hip/hip_runtime.h>

#define HW_ 3136
#define EPSV 1e-5f

typedef __bf16 bf16x8 __attribute__((ext_vector_type(8)));
typedef float f32x4 __attribute__((ext_vector_type(4)));
typedef unsigned short u16x8 __attribute__((ext_vector_type(8)));

__device__ __forceinline__ unsigned short f2bf(float f) {
    unsigned u = __builtin_bit_cast(unsigned, f);
    unsigned r = u + 0x7fffu + ((u >> 16) & 1u);
    return (unsigned short)(r >> 16);
}

__device__ __forceinline__ float gelu_exact(float x) {
    return 0.5f * x * (1.0f + erff(x * 0.70710678118654752440f));
}

// Out[b, m0+row, p0+col] = epi( scale[o]*(sum_k W[o,k]*In[b,k,p]) + shift[o] )
// Tile: BM=128, BN=64, BK=32. 4 waves, each 64x32 via 4x2 mfma_f32_16x16x32_bf16.
template<int KDIM, int EPI, int OUTCH>
__global__ __launch_bounds__(256)
void gemm_fused(const float* __restrict__ W,
                const float* __restrict__ In,
                float* __restrict__ Out,
                const float* __restrict__ pb,
                const float* __restrict__ pg,
                const float* __restrict__ pbe,
                const float* __restrict__ pm,
                const float* __restrict__ pv,
                const float* __restrict__ res)
{
    __shared__ __align__(16) unsigned short As[128 * 32]; // [row][k], 64B rows, XOR swizzled
    __shared__ __align__(16) unsigned short Bs[64 * 32];  // [n][k],  64B rows, XOR swizzled

    const int t    = threadIdx.x;
    const int lane = t & 63;
    const int wave = t >> 6;
    const int wm   = wave >> 1;   // 0..1
    const int wn   = wave & 1;    // 0..1
    const int m0   = blockIdx.x * 128;
    const int p0   = blockIdx.y * 64;
    const int b    = blockIdx.z;
    const float* Inb = In + (size_t)b * KDIM * HW_;

    f32x4 acc[4][2] = {};

    const int arow = t >> 3;   // 0..31 (A stage row within rep)
    const int ac4  = t & 7;    // float4 index along K
    const int bn_  = t & 63;   // B stage n
    const int bcg  = t >> 6;   // B stage k-group (0..3)

    for (int k0 = 0; k0 < KDIM; k0 += 32) {
        __syncthreads();
        // ---- stage A: 128 rows x 32 k (W row-major, K contiguous) ----
        #pragma unroll
        for (int rr = 0; rr < 4; ++rr) {
            int row = rr * 32 + arow;
            const float4 f4 = *(const float4*)(&W[(size_t)(m0 + row) * KDIM + k0 + ac4 * 4]);
            unsigned long long pk =
                  (unsigned long long)f2bf(f4.x)
                | ((unsigned long long)f2bf(f4.y) << 16)
                | ((unsigned long long)f2bf(f4.z) << 32)
                | ((unsigned long long)f2bf(f4.w) << 48);
            int off = (row * 64 + ac4 * 8) ^ ((row & 7) << 4);
            *(unsigned long long*)((char*)As + off) = pk;
        }
        // ---- stage B: 64 n x 32 k, transposed from In[k][p] ----
        {
            u16x8 v;
            #pragma unroll
            for (int j = 0; j < 8; ++j) {
                float f = Inb[(size_t)(k0 + bcg * 8 + j) * HW_ + p0 + bn_];
                v[j] = f2bf(f);
            }
            int off = (bn_ * 64 + bcg * 16) ^ ((bn_ & 7) << 4);
            *(u16x8*)((char*)Bs + off) = v;
        }
        __syncthreads();

        // ---- fragments + MFMA ----
        const int kb = (lane >> 4) * 16; // byte offset of this lane's 8 k's
        bf16x8 afr[4], bfr[2];
        #pragma unroll
        for (int mf = 0; mf < 4; ++mf) {
            int row = wm * 64 + mf * 16 + (lane & 15);
            afr[mf] = __builtin_bit_cast(bf16x8,
                *(const u16x8*)((const char*)As + ((row * 64 + kb) ^ ((row & 7) << 4))));
        }
        #pragma unroll
        for (int nf = 0; nf < 2; ++nf) {
            int n = wn * 32 + nf * 16 + (lane & 15);
            bfr[nf] = __builtin_bit_cast(bf16x8,
                *(const u16x8*)((const char*)Bs + ((n * 64 + kb) ^ ((n & 7) << 4))));
        }
        #pragma unroll
        for (int mf = 0; mf < 4; ++mf)
            #pragma unroll
            for (int nf = 0; nf < 2; ++nf)
                acc[mf][nf] = __builtin_amdgcn_mfma_f32_16x16x32_bf16(
                    afr[mf], bfr[nf], acc[mf][nf], 0, 0, 0);
    }

    // ---- epilogue: BN (+gelu / +residual) ----
    float* Outb = Out + (size_t)b * OUTCH * HW_;
    const float* resb = res + (size_t)b * OUTCH * HW_; // only used when EPI==2 (OUTCH==384)
    #pragma unroll
    for (int mf = 0; mf < 4; ++mf) {
        #pragma unroll
        for (int r = 0; r < 4; ++r) {
            int o = m0 + wm * 64 + mf * 16 + (lane >> 4) * 4 + r;
            float inv = pg[o] / sqrtf(pv[o] + EPSV);
            float sh  = (pb[o] - pm[o]) * inv + pbe[o];
            #pragma unroll
            for (int nf = 0; nf < 2; ++nf) {
                int col = p0 + wn * 32 + nf * 16 + (lane & 15);
                float val = acc[mf][nf][r] * inv + sh;
                if (EPI == 1) val = gelu_exact(val);
                if (EPI == 2) val += resb[(size_t)o * HW_ + col];
                Outb[(size_t)o * HW_ + col] = val;
            }
        }
    }
}

// x_j[h,w] = max(0, v - min(min_{h'==h mod2, h'!=h} v[h',w], min_{w'==w mod2, w'!=w} v[h,w']))
// One block per (b,c) plane; reads y[:, c], writes y[:, 384+c].
__global__ __launch_bounds__(256)
void mrconv_xj(float* __restrict__ y)
{
    __shared__ float pl[3136];
    __shared__ float colM1[2][56], colM2[2][56], rowM1[2][56], rowM2[2][56];
    const int t = threadIdx.x;
    const int c = blockIdx.x;
    const int b = blockIdx.y;
    const float* src = y + ((size_t)b * 768 + c) * HW_;
    float* dst       = y + ((size_t)b * 768 + 384 + c) * HW_;

    for (int i = t; i < 3136; i += 256) pl[i] = src[i];
    __syncthreads();

    if (t < 224) {
        int isRow = (t >= 112);
        int q   = isRow ? (t - 112) : t;
        int idx = q % 56;      // column w (col-task) or row h (row-task)
        int par = q / 56;      // parity
        float m1 = 3.4e38f, m2 = 3.4e38f;
        if (!isRow) {
            for (int h = par; h < 56; h += 2) {
                float v = pl[h * 56 + idx];
                if (v < m1) { m2 = m1; m1 = v; } else if (v < m2) { m2 = v; }
            }
            colM1[par][idx] = m1; colM2[par][idx] = m2;
        } else {
            for (int w = par; w < 56; w += 2) {
                float v = pl[idx * 56 + w];
                if (v < m1) { m2 = m1; m1 = v; } else if (v < m2) { m2 = v; }
            }
            rowM1[par][idx] = m1; rowM2[par][idx] = m2;
        }
    }
    __syncthreads();

    for (int i = t; i < 3136; i += 256) {
        int h = i / 56, w = i - h * 56;
        float v = pl[i];
        float c1 = colM1[h & 1][w];
        float mh = (v > c1) ? c1 : colM2[h & 1][w];
        float r1 = rowM1[w & 1][h];
        float mw = (v > r1) ? r1 : rowM2[w & 1][h];
        float mn = fminf(mh, mw);
        dst[i] = fmaxf(0.0f, v - mn);
    }
}

extern "C" void kernel_launch(void* const* d_in, const int* in_sizes, int n_in,
                              void* d_out, int out_size, void* d_ws, size_t ws_size,
                              hipStream_t stream)
{
    const float* x      = (const float*)d_in[0];
    const float* fc1_w  = (const float*)d_in[1];
    const float* fc1_b  = (const float*)d_in[2];
    const float* fc1_g  = (const float*)d_in[3];
    const float* fc1_be = (const float*)d_in[4];
    const float* fc1_m  = (const float*)d_in[5];
    const float* fc1_v  = (const float*)d_in[6];
    const float* gc_w   = (const float*)d_in[7];
    const float* gc_b   = (const float*)d_in[8];
    const float* gc_g   = (const float*)d_in[9];
    const float* gc_be  = (const float*)d_in[10];
    const float* gc_m   = (const float*)d_in[11];
    const float* gc_v   = (const float*)d_in[12];
    const float* fc2_w  = (const float*)d_in[13];
    const float* fc2_b  = (const float*)d_in[14];
    const float* fc2_g  = (const float*)d_in[15];
    const float* fc2_be = (const float*)d_in[16];
    const float* fc2_m  = (const float*)d_in[17];
    const float* fc2_v  = (const float*)d_in[18];

    float* y = (float*)d_ws;                       // [16][768][3136] fp32
    float* g = y + (size_t)16 * 768 * HW_;         // [16][768][3136] fp32
    float* out = (float*)d_out;                    // [16][384][3136] fp32

    dim3 blk(256);
    // h1 = bn(fc1 @ x) -> y[:, 0:384]
    gemm_fused<384, 0, 768><<<dim3(3, 49, 16), blk, 0, stream>>>(
        fc1_w, x, y, fc1_b, fc1_g, fc1_be, fc1_m, fc1_v, nullptr);
    // x_j -> y[:, 384:768]
    mrconv_xj<<<dim3(384, 16), blk, 0, stream>>>(y);
    // g = gelu(bn(gc @ y))
    gemm_fused<768, 1, 768><<<dim3(6, 49, 16), blk, 0, stream>>>(
        gc_w, y, g, gc_b, gc_g, gc_be, gc_m, gc_v, nullptr);
    // out = bn(fc2 @ g) + x
    gemm_fused<768, 2, 384><<<dim3(3, 49, 16), blk, 0, stream>>>(
        fc2_w, g, out, fc2_b, fc2_g, fc2_be, fc2_m, fc2_v, x);
}

// Round 2
// 307.000 us; speedup vs baseline: 2.2354x; 2.2354x over previous
//
#include <hip/hip_runtime.h>

#define P_ 3136
#define NTOT 50176
#define EPSV 1e-5f

typedef __bf16 bf16x8 __attribute__((ext_vector_type(8)));
typedef float f32x4 __attribute__((ext_vector_type(4)));
typedef unsigned short u16x8 __attribute__((ext_vector_type(8)));
typedef unsigned short u16x4 __attribute__((ext_vector_type(4)));

__device__ __forceinline__ unsigned short f2bf(float f) {
    unsigned u = __builtin_bit_cast(unsigned, f);
    unsigned r = u + 0x7fffu + ((u >> 16) & 1u);
    return (unsigned short)(r >> 16);
}
__device__ __forceinline__ float bf2f(unsigned short h) {
    unsigned u = ((unsigned)h) << 16;
    return __builtin_bit_cast(float, u);
}
__device__ __forceinline__ float gelu_exact(float x) {
    return 0.5f * x * (1.0f + erff(x * 0.70710678118654752440f));
}
__device__ __forceinline__ void gload16(const void* g, void* l) {
    __builtin_amdgcn_global_load_lds(
        (const __attribute__((address_space(1))) void*)g,
        (__attribute__((address_space(3))) void*)l, 16, 0, 0);
}

// ---------------- prep: weights fp32 -> bf16 ----------------
__global__ __launch_bounds__(256)
void prep_w(const float* __restrict__ w1, const float* __restrict__ w2,
            const float* __restrict__ w3,
            unsigned short* __restrict__ o1, unsigned short* __restrict__ o2,
            unsigned short* __restrict__ o3)
{
    int i = blockIdx.x * 256 + threadIdx.x;
    const int n1 = 384 * 384 / 4, n2 = 768 * 768 / 4;
    const float* src; unsigned short* dst; int j;
    if (i < n1)           { src = w1; dst = o1; j = i; }
    else if (i < n1 + n2) { src = w2; dst = o2; j = i - n1; }
    else                  { src = w3; dst = o3; j = i - n1 - n2; }
    float4 f = *(const float4*)(src + (size_t)j * 4);
    u16x4 pk = { f2bf(f.x), f2bf(f.y), f2bf(f.z), f2bf(f.w) };
    *(u16x4*)(dst + (size_t)j * 4) = pk;
}

// ---------------- prep: BN scale/shift ----------------
__global__ __launch_bounds__(256)
void prep_bn(const float* b1, const float* g1, const float* be1, const float* m1, const float* v1,
             const float* b2, const float* g2, const float* be2, const float* m2, const float* v2,
             const float* b3, const float* g3, const float* be3, const float* m3, const float* v3,
             float* bn1, float* bn2, float* bn3)
{
    int i = blockIdx.x * 256 + threadIdx.x;
    const float *pb, *pg, *pbe, *pm, *pv; float* dst; int o, M;
    if (i < 384)       { pb=b1; pg=g1; pbe=be1; pm=m1; pv=v1; dst=bn1; o=i;        M=384; }
    else if (i < 1152) { pb=b2; pg=g2; pbe=be2; pm=m2; pv=v2; dst=bn2; o=i-384;    M=768; }
    else               { pb=b3; pg=g3; pbe=be3; pm=m3; pv=v3; dst=bn3; o=i-1152;   M=384; }
    float inv = pg[o] / sqrtf(pv[o] + EPSV);
    dst[o]     = inv;
    dst[M + o] = (pb[o] - pm[o]) * inv + pbe[o];
}

// ---------------- prep: x [b][c][p] fp32 -> xT [bp][c] bf16 ----------------
__global__ __launch_bounds__(256)
void prep_xT(const float* __restrict__ x, unsigned short* __restrict__ xT)
{
    __shared__ float tl[64][65];
    const int t = threadIdx.x;
    const int c0 = blockIdx.x * 64;
    const int p0 = blockIdx.y * 64;
    const int b  = blockIdx.z;
    const float* xb = x + ((size_t)b * 384 + c0) * P_ + p0;
    {
        int c = t >> 2, j0 = (t & 3) * 16;
        #pragma unroll
        for (int j = 0; j < 16; j += 4) {
            float4 f4 = *(const float4*)(xb + (size_t)c * P_ + j0 + j);
            tl[c][j0 + j]     = f4.x; tl[c][j0 + j + 1] = f4.y;
            tl[c][j0 + j + 2] = f4.z; tl[c][j0 + j + 3] = f4.w;
        }
    }
    __syncthreads();
    {
        int p = t >> 2, c1 = (t & 3) * 16;
        unsigned short buf[16];
        #pragma unroll
        for (int j = 0; j < 16; ++j) buf[j] = f2bf(tl[c1 + j][p]);
        unsigned short* dst = xT + ((size_t)b * P_ + p0 + p) * 384 + c0 + c1;
        *(u16x8*)dst       = *(u16x8*)buf;
        *(u16x8*)(dst + 8) = *(u16x8*)(buf + 8);
    }
}

// ---------------- GEMM: Out[bp][o] = epi(inv[o]*(W@In)[o][bp] + sh[o]) ----------------
// A = W [MDIM][KDIM] bf16 rowmajor; B = In [NTOT][KDIM] bf16 rowmajor (k-contig).
// BM=128, BN=128, BK=64. 4 waves 2x2, each 64x64 via 4x4 frags of 16x16x32.
// EPI 0: bf16 out stride 768. EPI 1: +gelu, bf16 out stride 768.
// EPI 2: fp32 out channel-major [b][o][p] + residual.
template<int KDIM, int MDIM, int EPI>
__global__ __launch_bounds__(256)
void gemm_bf16(const unsigned short* __restrict__ W,
               const unsigned short* __restrict__ In,
               void* __restrict__ OutV,
               const float* __restrict__ bnp,
               const float* __restrict__ res)
{
    __shared__ __align__(16) unsigned short As[128 * 64];
    __shared__ __align__(16) unsigned short Bs[128 * 64];
    const int t    = threadIdx.x;
    const int lane = t & 63;
    const int wave = t >> 6;
    const int wm = wave >> 1, wn = wave & 1;
    const int fr = lane & 15, fg = lane >> 4;
    const int m0 = blockIdx.x * 128;
    const int n0 = blockIdx.y * 128;

    // staging: dest byte = i*4096 + t*16 (linear LDS); row = dest>>7.
    // swizzle inverse applied to global source column: pos = dest ^ ((row&7)<<4).
    const int pcu = (((t & 7) ^ ((t >> 3) & 7)) << 3); // source col offset in ushorts
    const unsigned short* asrc[4];
    const unsigned short* bsrc[4];
    #pragma unroll
    for (int i = 0; i < 4; ++i) {
        int row = i * 32 + (t >> 3);
        asrc[i] = W  + (size_t)(m0 + row) * KDIM + pcu;
        bsrc[i] = In + (size_t)(n0 + row) * KDIM + pcu;
    }

    f32x4 acc[4][4] = {};

    for (int k0 = 0; k0 < KDIM; k0 += 64) {
        __syncthreads();
        #pragma unroll
        for (int i = 0; i < 4; ++i)
            gload16(asrc[i] + k0, (char*)As + i * 4096 + wave * 1024);
        #pragma unroll
        for (int i = 0; i < 4; ++i)
            gload16(bsrc[i] + k0, (char*)Bs + i * 4096 + wave * 1024);
        __syncthreads();

        #pragma unroll
        for (int kk = 0; kk < 2; ++kk) {
            bf16x8 af[4], bfr[4];
            const int kcol = (kk * 64 + fg * 16) ^ ((fr & 7) << 4);
            #pragma unroll
            for (int mf = 0; mf < 4; ++mf) {
                int row = wm * 64 + mf * 16 + fr;
                af[mf] = __builtin_bit_cast(bf16x8,
                    *(const u16x8*)((const char*)As + row * 128 + kcol));
            }
            #pragma unroll
            for (int nf = 0; nf < 4; ++nf) {
                int row = wn * 64 + nf * 16 + fr;
                bfr[nf] = __builtin_bit_cast(bf16x8,
                    *(const u16x8*)((const char*)Bs + row * 128 + kcol));
            }
            #pragma unroll
            for (int mf = 0; mf < 4; ++mf)
                #pragma unroll
                for (int nf = 0; nf < 4; ++nf)
                    acc[mf][nf] = __builtin_amdgcn_mfma_f32_16x16x32_bf16(
                        af[mf], bfr[nf], acc[mf][nf], 0, 0, 0);
        }
    }

    const int obase = m0 + wm * 64;
    if (EPI < 2) {
        unsigned short* Out = (unsigned short*)OutV;
        #pragma unroll
        for (int mf = 0; mf < 4; ++mf) {
            int o0 = obase + mf * 16 + fg * 4;
            f32x4 inv = *(const f32x4*)(bnp + o0);
            f32x4 sh  = *(const f32x4*)(bnp + MDIM + o0);
            #pragma unroll
            for (int nf = 0; nf < 4; ++nf) {
                int col = n0 + wn * 64 + nf * 16 + fr;
                u16x4 pk;
                #pragma unroll
                for (int r = 0; r < 4; ++r) {
                    float v = acc[mf][nf][r] * inv[r] + sh[r];
                    if (EPI == 1) v = gelu_exact(v);
                    pk[r] = f2bf(v);
                }
                *(u16x4*)(Out + (size_t)col * 768 + o0) = pk;
            }
        }
    } else {
        float* Out = (float*)OutV;
        #pragma unroll
        for (int mf = 0; mf < 4; ++mf) {
            int o0 = obase + mf * 16 + fg * 4;
            f32x4 inv = *(const f32x4*)(bnp + o0);
            f32x4 sh  = *(const f32x4*)(bnp + MDIM + o0);
            #pragma unroll
            for (int nf = 0; nf < 4; ++nf) {
                int col = n0 + wn * 64 + nf * 16 + fr;
                int b   = col / P_;
                int p   = col - b * P_;
                size_t base = (size_t)b * 384 * P_ + p;
                #pragma unroll
                for (int r = 0; r < 4; ++r) {
                    int o = o0 + r;
                    float v = acc[mf][nf][r] * inv[r] + sh[r] + res[base + (size_t)o * P_];
                    Out[base + (size_t)o * P_] = v;
                }
            }
        }
    }
}

// ---------------- mrconv pass 1: per-(b, w|h) parity mins ----------------
// mins: cm1,cm2,rm1,rm2 each [16][2][56][384] fp32, consecutive.
#define MINSEG (16 * 2 * 56 * 384)
__global__ __launch_bounds__(384)
void mr_min(const unsigned short* __restrict__ y, float* __restrict__ mins)
{
    const int c = threadIdx.x;
    const int q = blockIdx.x;  // 0..55 col-task (w), 56..111 row-task (h)
    const int b = blockIdx.y;
    const unsigned short* yb = y + (size_t)b * P_ * 768;
    float m1e = 3.4e38f, m2e = 3.4e38f, m1o = 3.4e38f, m2o = 3.4e38f;
    if (q < 56) {
        int w = q;
        for (int h = 0; h < 56; h += 2) {
            float v0 = bf2f(yb[(size_t)(h * 56 + w) * 768 + c]);
            float v1 = bf2f(yb[(size_t)((h + 1) * 56 + w) * 768 + c]);
            if (v0 < m1e) { m2e = m1e; m1e = v0; } else if (v0 < m2e) m2e = v0;
            if (v1 < m1o) { m2o = m1o; m1o = v1; } else if (v1 < m2o) m2o = v1;
        }
        float* cm1 = mins;
        float* cm2 = mins + MINSEG;
        cm1[((b * 2 + 0) * 56 + w) * 384 + c] = m1e;
        cm1[((b * 2 + 1) * 56 + w) * 384 + c] = m1o;
        cm2[((b * 2 + 0) * 56 + w) * 384 + c] = m2e;
        cm2[((b * 2 + 1) * 56 + w) * 384 + c] = m2o;
    } else {
        int h = q - 56;
        for (int w = 0; w < 56; w += 2) {
            float v0 = bf2f(yb[(size_t)(h * 56 + w) * 768 + c]);
            float v1 = bf2f(yb[(size_t)(h * 56 + w + 1) * 768 + c]);
            if (v0 < m1e) { m2e = m1e; m1e = v0; } else if (v0 < m2e) m2e = v0;
            if (v1 < m1o) { m2o = m1o; m1o = v1; } else if (v1 < m2o) m2o = v1;
        }
        float* rm1 = mins + 2 * MINSEG;
        float* rm2 = mins + 3 * MINSEG;
        rm1[((b * 2 + 0) * 56 + h) * 384 + c] = m1e;
        rm1[((b * 2 + 1) * 56 + h) * 384 + c] = m1o;
        rm2[((b * 2 + 0) * 56 + h) * 384 + c] = m2e;
        rm2[((b * 2 + 1) * 56 + h) * 384 + c] = m2o;
    }
}

// ---------------- mrconv pass 2: combine -> y[:, 384:768] ----------------
__global__ __launch_bounds__(384)
void mr_comb(unsigned short* __restrict__ y, const float* __restrict__ mins)
{
    const int c = threadIdx.x;
    const int h = blockIdx.x;
    const int b = blockIdx.y;
    unsigned short* yb = y + (size_t)b * P_ * 768;
    const float* cm1 = mins;
    const float* cm2 = mins + MINSEG;
    const float* rm1 = mins + 2 * MINSEG;
    const float* rm2 = mins + 3 * MINSEG;
    const int parh = h & 1;
    float r1e = rm1[((b * 2 + 0) * 56 + h) * 384 + c];
    float r2e = rm2[((b * 2 + 0) * 56 + h) * 384 + c];
    float r1o = rm1[((b * 2 + 1) * 56 + h) * 384 + c];
    float r2o = rm2[((b * 2 + 1) * 56 + h) * 384 + c];
    #pragma unroll 2
    for (int w = 0; w < 56; ++w) {
        float v  = bf2f(yb[(size_t)(h * 56 + w) * 768 + c]);
        float c1 = cm1[((b * 2 + parh) * 56 + w) * 384 + c];
        float c2 = cm2[((b * 2 + parh) * 56 + w) * 384 + c];
        float mh = v > c1 ? c1 : c2;
        float rw1 = (w & 1) ? r1o : r1e;
        float rw2 = (w & 1) ? r2o : r2e;
        float mw = v > rw1 ? rw1 : rw2;
        float xj = fmaxf(0.0f, v - fminf(mh, mw));
        yb[(size_t)(h * 56 + w) * 768 + 384 + c] = f2bf(xj);
    }
}

extern "C" void kernel_launch(void* const* d_in, const int* in_sizes, int n_in,
                              void* d_out, int out_size, void* d_ws, size_t ws_size,
                              hipStream_t stream)
{
    const float* x      = (const float*)d_in[0];
    const float* fc1_w  = (const float*)d_in[1];
    const float* fc1_b  = (const float*)d_in[2];
    const float* fc1_g  = (const float*)d_in[3];
    const float* fc1_be = (const float*)d_in[4];
    const float* fc1_m  = (const float*)d_in[5];
    const float* fc1_v  = (const float*)d_in[6];
    const float* gc_w   = (const float*)d_in[7];
    const float* gc_b   = (const float*)d_in[8];
    const float* gc_g   = (const float*)d_in[9];
    const float* gc_be  = (const float*)d_in[10];
    const float* gc_m   = (const float*)d_in[11];
    const float* gc_v   = (const float*)d_in[12];
    const float* fc2_w  = (const float*)d_in[13];
    const float* fc2_b  = (const float*)d_in[14];
    const float* fc2_g  = (const float*)d_in[15];
    const float* fc2_be = (const float*)d_in[16];
    const float* fc2_m  = (const float*)d_in[17];
    const float* fc2_v  = (const float*)d_in[18];

    char* ws = (char*)d_ws;
    unsigned short* y   = (unsigned short*)ws;                       // [NTOT][768] bf16
    unsigned short* g   = y + (size_t)NTOT * 768;                    // [NTOT][768] bf16
    unsigned short* xT  = g + (size_t)NTOT * 768;                    // [NTOT][384] bf16
    unsigned short* wb1 = xT + (size_t)NTOT * 384;                   // [384][384]
    unsigned short* wb2 = wb1 + 384 * 384;                           // [768][768]
    unsigned short* wb3 = wb2 + 768 * 768;                           // [384][768]
    float* bn1 = (float*)(wb3 + 384 * 768);                          // [2][384]
    float* bn2 = bn1 + 2 * 384;                                      // [2][768]
    float* bn3 = bn2 + 2 * 768;                                      // [2][384]
    float* mins = bn3 + 2 * 384;                                     // 4 * MINSEG

    prep_w<<<1008, 256, 0, stream>>>(fc1_w, gc_w, fc2_w, wb1, wb2, wb3);
    prep_bn<<<6, 256, 0, stream>>>(fc1_b, fc1_g, fc1_be, fc1_m, fc1_v,
                                   gc_b, gc_g, gc_be, gc_m, gc_v,
                                   fc2_b, fc2_g, fc2_be, fc2_m, fc2_v,
                                   bn1, bn2, bn3);
    prep_xT<<<dim3(6, 49, 16), 256, 0, stream>>>(x, xT);

    // y[:, 0:384] = bn(fc1 @ x)
    gemm_bf16<384, 384, 0><<<dim3(3, 392), 256, 0, stream>>>(wb1, xT, y, bn1, nullptr);
    // y[:, 384:768] = mrconv
    mr_min<<<dim3(112, 16), 384, 0, stream>>>(y, mins);
    mr_comb<<<dim3(56, 16), 384, 0, stream>>>(y, mins);
    // g = gelu(bn(gc @ y))
    gemm_bf16<768, 768, 1><<<dim3(6, 392), 256, 0, stream>>>(wb2, y, g, bn2, nullptr);
    // out = bn(fc2 @ g) + x
    gemm_bf16<768, 384, 2><<<dim3(3, 392), 256, 0, stream>>>(wb3, g, (void*)d_out, bn3, x);
}